// Round 3
// baseline (461.771 us; speedup 1.0000x reference)
//
#include <hip/hip_runtime.h>
#include <hip/hip_bf16.h>
#include <cstdint>

typedef __attribute__((ext_vector_type(8))) short bf16x8;
typedef __attribute__((ext_vector_type(4))) float f32x4;
typedef __attribute__((ext_vector_type(4))) unsigned short u16x4;
typedef __attribute__((ext_vector_type(8))) unsigned short u16x8;

__device__ __forceinline__ unsigned short f2bf(float f) {
    unsigned int u = __float_as_uint(f);
    unsigned int r = (u + 0x7fffu + ((u >> 16) & 1u)) >> 16;
    return (unsigned short)r;
}

__device__ __forceinline__ float tanh_fast(float x) {
    return 1.0f - 2.0f / (__expf(2.0f * x) + 1.0f);
}

#define GLDS(SRC, DST) __builtin_amdgcn_global_load_lds(                         \
        (const __attribute__((address_space(1))) void*)(SRC),                    \
        (__attribute__((address_space(3))) void*)(DST), 16, 0, 0)

// ---------- K-1: fp32 -> bf16 convert of key_in into FRAGMENT-TILED layout ----
// out[panel][kt][chunk c=rb*64+kg*16+r][8]  (panel=b*32+ks : 128 rows; kt: 32 K)
// chunk holds row R=panel*128+rb*16+r, k = kt*32+kg*8 .. +8
__global__ __launch_bounds__(256) void key_tile_kernel(
        const float* __restrict__ in, unsigned short* __restrict__ out) {
    const int panel = blockIdx.x;   // 0..511
    const int kt = blockIdx.y;      // 0..31
    const int t = threadIdx.x;
#pragma unroll
    for (int cc = 0; cc < 2; ++cc) {
        const int c = cc * 256 + t;
        const int rb = c >> 6, kg = (c >> 4) & 3, r = c & 15;
        const size_t R = (size_t)panel * 128 + rb * 16 + r;
        const float* src = in + R * 1024 + kt * 32 + kg * 8;
        const float4 v0 = *reinterpret_cast<const float4*>(src);
        const float4 v1 = *reinterpret_cast<const float4*>(src + 4);
        u16x8 u;
        u[0] = f2bf(v0.x); u[1] = f2bf(v0.y); u[2] = f2bf(v0.z); u[3] = f2bf(v0.w);
        u[4] = f2bf(v1.x); u[5] = f2bf(v1.y); u[6] = f2bf(v1.z); u[7] = f2bf(v1.w);
        *reinterpret_cast<u16x8*>(out + (((size_t)panel * 32 + kt) * 512 + c) * 8) = u;
    }
}

// ---------- K0: w_v -> bf16 fragment-tiled B: out[h][kt][cb*64+kg*16+cc][8] ----
// chunk holds col e=h*128+cb*16+cc, k(f) = kt*32+kg*8 .. +8
__global__ __launch_bounds__(256) void wv_tile_kernel(
        const float* __restrict__ wv, unsigned short* __restrict__ out) {
    __shared__ float tile[32][129];
    const int h = blockIdx.x;    // 0..7
    const int kt = blockIdx.y;   // 0..31
    const int t = threadIdx.x;
    for (int i = t; i < 1024; i += 256) {       // i = float4 index; 32 rows x 32 f4
        const int fl = i >> 5;
        const int e4 = (i & 31) * 4;
        const float4 v = *reinterpret_cast<const float4*>(
            wv + (size_t)(kt * 32 + fl) * 1024 + h * 128 + e4);
        tile[fl][e4 + 0] = v.x; tile[fl][e4 + 1] = v.y;
        tile[fl][e4 + 2] = v.z; tile[fl][e4 + 3] = v.w;
    }
    __syncthreads();
#pragma unroll
    for (int cc2 = 0; cc2 < 2; ++cc2) {
        const int c = cc2 * 256 + t;
        const int cb = c >> 6, kg = (c >> 4) & 3, ccl = c & 15;
        const int e_local = cb * 16 + ccl;
        u16x8 u;
#pragma unroll
        for (int j = 0; j < 8; ++j) u[j] = f2bf(tile[kg * 8 + j][e_local]);
        *reinterpret_cast<u16x8*>(out + (((size_t)h * 32 + kt) * 512 + c) * 8) = u;
    }
}

// ---------- K1: q projection ----------
__global__ __launch_bounds__(128) void qproj_kernel(
        const float* __restrict__ query, const float* __restrict__ w_q,
        float* __restrict__ ws_q) {
    __shared__ float qs[1024];
    int bh = blockIdx.x;
    int b = bh >> 3, h = bh & 7;
    int t = threadIdx.x;
    for (int i = t; i < 1024; i += 128) qs[i] = query[(size_t)b * 1024 + i];
    __syncthreads();
    float acc = 0.f;
    const float* wcol = w_q + h * 128 + t;
    for (int f = 0; f < 1024; ++f) acc += qs[f] * wcol[(size_t)f * 1024];
    ws_q[(size_t)bh * 128 + t] = acc;
}

// ---------- K2: conv1d location features ----------
__global__ __launch_bounds__(256) void loc_conv_kernel(
        const float* __restrict__ pa, const float* __restrict__ conv_w,
        const float* __restrict__ conv_b, float* __restrict__ ws_loc) {
    __shared__ float pas[8][258];
    __shared__ float cw[240];
    __shared__ float cb[16];
    int b = blockIdx.x, k0 = blockIdx.y * 256;
    int t = threadIdx.x;
    for (int i = t; i < 8 * 258; i += 256) {
        int hh = i / 258, kk = i % 258;
        int gk = k0 + kk - 1;
        pas[hh][kk] = (gk >= 0 && gk < 4096) ? pa[((size_t)(b * 8 + hh)) * 4096 + gk] : 0.f;
    }
    if (t < 240) cw[t] = conv_w[t];
    if (t < 10) cb[t] = conv_b[t];
    __syncthreads();
#pragma unroll
    for (int c = 0; c < 10; ++c) {
        float acc = cb[c];
#pragma unroll
        for (int hh = 0; hh < 8; ++hh) {
            acc += pas[hh][t] * cw[(c * 8 + hh) * 3 + 0]
                 + pas[hh][t + 1] * cw[(c * 8 + hh) * 3 + 1]
                 + pas[hh][t + 2] * cw[(c * 8 + hh) * 3 + 2];
        }
        ws_loc[((size_t)(b * 10 + c)) * 4096 + k0 + t] = acc;
    }
}

// ---------- K2b: le[b,k,d] = tanh(sum_c loc[b,c,k]*w_u[c,d])  (head-indep) ----
__global__ __launch_bounds__(256) void loc_energy_kernel(
        const float* __restrict__ ws_loc, const float* __restrict__ w_u,
        float* __restrict__ le) {
    __shared__ float loc_s[10][128];
    __shared__ float wu_s[10][128];
    const int b = blockIdx.x, k0 = blockIdx.y * 128;
    const int t = threadIdx.x;
    for (int i = t; i < 1280; i += 256) {
        const int c = i >> 7, r = i & 127;
        loc_s[c][r] = ws_loc[((size_t)(b * 10 + c)) * 4096 + k0 + r];
        wu_s[c][r] = w_u[i];
    }
    __syncthreads();
    const int k = t >> 1;
    const int d0 = (t & 1) * 64;
    float lc[10];
#pragma unroll
    for (int c = 0; c < 10; ++c) lc[c] = loc_s[c][k];
    float* dst = le + ((size_t)(b * 4096) + k0 + k) * 128 + d0;
#pragma unroll
    for (int dd = 0; dd < 64; dd += 4) {
        float4 o;
#pragma unroll
        for (int j = 0; j < 4; ++j) {
            float s = 0.f;
#pragma unroll
            for (int c = 0; c < 10; ++c) s += lc[c] * wu_s[c][d0 + dd + j];
            ((float*)&o)[j] = tanh_fast(s);
        }
        *reinterpret_cast<float4*>(dst + dd) = o;
    }
}

// ---------- K3: fused bf16 MFMA GEMM + energy + score ----------
// BM=128, BN=128 (one head), BK=32; 4 waves 2x2; dbuf; fragment-tiled LDS.
// AMODE 0: A pre-tiled bf16 via global_load_lds; le precomputed
// AMODE 1: A fp32 reg-convert into tiled LDS; le precomputed
// AMODE 2: A fp32 reg-convert; loc energy inline (minimal ws)
template<int AMODE>
__global__ __launch_bounds__(256) void gemm_score_kernel(
        const float* __restrict__ key_f32, const unsigned short* __restrict__ key_tiled,
        const unsigned short* __restrict__ wvT_tiled,
        const float* __restrict__ le,
        const float* __restrict__ ws_q, const float* __restrict__ ws_loc,
        const float* __restrict__ w_u, const float* __restrict__ bias,
        const float* __restrict__ score_w, const float* __restrict__ score_b,
        float* __restrict__ align_out) {
    __shared__ __align__(16) unsigned short As[2][4096];
    __shared__ __align__(16) unsigned short Bs[2][4096];
    __shared__ float loc_sm[AMODE == 2 ? 1280 : 1];
    __shared__ float wu_sm[AMODE == 2 ? 1280 : 1];
    __shared__ float qb_sm[128], sw_sm[128];
    __shared__ float partial[256];

    const int t = threadIdx.x;
    const int lane = t & 63, wid = t >> 6;
    const int wm = wid >> 1, wn = wid & 1;

    // XCD swizzle: 8 head-blocks of one A-panel contiguous on one XCD
    const int fid = blockIdx.x;
    const int x = fid & 7, j = fid >> 3;
    const int bm = x * 64 + (j >> 3);
    const int h = j & 7;
    const int b = bm >> 5;
    const int kk0 = (bm & 31) << 7;

    if (t < 128) {
        qb_sm[t] = ws_q[(size_t)(b * 8 + h) * 128 + t] + bias[t];
        sw_sm[t] = score_w[t];
    }
    if (AMODE == 2) {
        for (int i = t; i < 1280; i += 256) {
            int c = i >> 7, r = i & 127;
            loc_sm[i] = ws_loc[((size_t)(b * 10 + c)) * 4096 + kk0 + r];
            wu_sm[i] = w_u[i];
        }
    }

    const unsigned short* aT = key_tiled + ((size_t)(b * 32 + (kk0 >> 7))) * 131072;
    const unsigned short* bT = wvT_tiled + (size_t)h * 131072;
    const float* aBaseF = key_f32 + ((size_t)(b * 4096 + kk0)) * 1024;

    f32x4 acc[4][4] = {};
    int cur = 0;

#define STAGE_B(BUF, KT) {                                                        \
        GLDS(bT + (KT) * 4096 + t * 8, &Bs[BUF][t * 8]);                          \
        GLDS(bT + (KT) * 4096 + 2048 + t * 8, &Bs[BUF][2048 + t * 8]); }

#define STAGE_A(BUF, KT) {                                                        \
        if (AMODE == 0) {                                                         \
            GLDS(aT + (KT) * 4096 + t * 8, &As[BUF][t * 8]);                      \
            GLDS(aT + (KT) * 4096 + 2048 + t * 8, &As[BUF][2048 + t * 8]);        \
        } else {                                                                  \
            _Pragma("unroll")                                                     \
            for (int cc_ = 0; cc_ < 2; ++cc_) {                                   \
                const int c_ = cc_ * 256 + t;                                     \
                const int rb_ = c_ >> 6, kg_ = (c_ >> 4) & 3, r_ = c_ & 15;       \
                const float* s_ = aBaseF + (size_t)(rb_ * 16 + r_) * 1024         \
                                  + (KT) * 32 + kg_ * 8;                          \
                const float4 v0_ = *reinterpret_cast<const float4*>(s_);          \
                const float4 v1_ = *reinterpret_cast<const float4*>(s_ + 4);      \
                u16x8 u_;                                                         \
                u_[0] = f2bf(v0_.x); u_[1] = f2bf(v0_.y);                         \
                u_[2] = f2bf(v0_.z); u_[3] = f2bf(v0_.w);                         \
                u_[4] = f2bf(v1_.x); u_[5] = f2bf(v1_.y);                         \
                u_[6] = f2bf(v1_.z); u_[7] = f2bf(v1_.w);                         \
                *reinterpret_cast<u16x8*>(&As[BUF][c_ * 8]) = u_;                 \
            }                                                                     \
        } }

    STAGE_A(0, 0);
    STAGE_B(0, 0);
    __syncthreads();

    for (int kt = 0; kt < 32; ++kt) {
        if (kt < 31) {
            STAGE_A(cur ^ 1, kt + 1);
            STAGE_B(cur ^ 1, kt + 1);
        }
        bf16x8 af[4], bg[4];
#pragma unroll
        for (int mf = 0; mf < 4; ++mf)
            af[mf] = *reinterpret_cast<const bf16x8*>(&As[cur][(wm * 4 + mf) * 512 + lane * 8]);
#pragma unroll
        for (int nf = 0; nf < 4; ++nf)
            bg[nf] = *reinterpret_cast<const bf16x8*>(&Bs[cur][(wn * 4 + nf) * 512 + lane * 8]);
#pragma unroll
        for (int mf = 0; mf < 4; ++mf)
#pragma unroll
            for (int nf = 0; nf < 4; ++nf)
                acc[mf][nf] = __builtin_amdgcn_mfma_f32_16x16x32_bf16(
                    af[mf], bg[nf], acc[mf][nf], 0, 0, 0);
        __syncthreads();
        cur ^= 1;
    }

    // epilogue: score = sum_d tanh(kproj + q + bias + le) * sw
    const float sb = score_b[0];
    const float* leBase = le + ((size_t)(b * 4096 + kk0)) * 128;
#pragma unroll
    for (int mf = 0; mf < 4; ++mf) {
#pragma unroll
        for (int jj = 0; jj < 4; ++jj) {
            const int row_l = wm * 64 + mf * 16 + ((lane >> 4) << 2) + jj;
            float sum = 0.f;
#pragma unroll
            for (int nf = 0; nf < 4; ++nf) {
                const int d = wn * 64 + nf * 16 + (lane & 15);
                float lev;
                if (AMODE == 2) {
                    float lr = 0.f;
#pragma unroll
                    for (int c = 0; c < 10; ++c)
                        lr += loc_sm[c * 128 + row_l] * wu_sm[c * 128 + d];
                    lev = tanh_fast(lr);
                } else {
                    lev = leBase[(size_t)row_l * 128 + d];
                }
                const float xv = acc[mf][nf][jj] + qb_sm[d] + lev;
                sum += tanh_fast(xv) * sw_sm[d];
            }
            sum += __shfl_xor(sum, 1);
            sum += __shfl_xor(sum, 2);
            sum += __shfl_xor(sum, 4);
            sum += __shfl_xor(sum, 8);
            if ((lane & 15) == 0) partial[row_l * 2 + wn] = sum;
        }
    }
    __syncthreads();
    if (t < 128) {
        align_out[(size_t)(b * 8 + h) * 4096 + kk0 + t] = partial[t * 2] + partial[t * 2 + 1] + sb;
    }
}

// ---------- K4: softmax over k ----------
__global__ __launch_bounds__(256) void softmax_kernel(float* __restrict__ align_o) {
    const int bh = blockIdx.x;
    float* row = align_o + (size_t)bh * 4096;
    const int t = threadIdx.x;
    float v[16];
    float m = -1e30f;
#pragma unroll
    for (int i = 0; i < 16; ++i) {
        v[i] = row[i * 256 + t];
        m = fmaxf(m, v[i]);
    }
#pragma unroll
    for (int off = 32; off; off >>= 1) m = fmaxf(m, __shfl_xor(m, off));
    __shared__ float sm[4], ss[4];
    const int wid = t >> 6;
    if ((t & 63) == 0) sm[wid] = m;
    __syncthreads();
    m = fmaxf(fmaxf(sm[0], sm[1]), fmaxf(sm[2], sm[3]));
    float s = 0.f;
#pragma unroll
    for (int i = 0; i < 16; ++i) {
        v[i] = __expf(v[i] - m);
        s += v[i];
    }
#pragma unroll
    for (int off = 32; off; off >>= 1) s += __shfl_xor(s, off);
    if ((t & 63) == 0) ss[wid] = s;
    __syncthreads();
    s = ss[0] + ss[1] + ss[2] + ss[3];
    const float inv = 1.f / s;
#pragma unroll
    for (int i = 0; i < 16; ++i) row[i * 256 + t] = v[i] * inv;
}

// ---------- K5: split-K context partials (float4) ----------
__global__ __launch_bounds__(256) void ctx_partial_kernel(
        const float* __restrict__ value, const float* __restrict__ align_o,
        float* __restrict__ pctx) {
    const int s = blockIdx.x;    // 0..31
    const int bh = blockIdx.y;   // 0..127
    const int b = bh >> 3, h = bh & 7;
    const int t = threadIdx.x;
    const int d4 = (t & 31) * 4;
    const int kg = t >> 5;       // 0..7
    const float* arow = align_o + (size_t)bh * 4096 + s * 128;
    const float* vbase = value + ((size_t)(b * 4096 + s * 128)) * 1024 + h * 128 + d4;
    float4 acc = {0.f, 0.f, 0.f, 0.f};
    for (int i = 0; i < 16; ++i) {
        const int kk = i * 8 + kg;
        const float a = arow[kk];
        const float4 v = *reinterpret_cast<const float4*>(vbase + (size_t)kk * 1024);
        acc.x += a * v.x; acc.y += a * v.y; acc.z += a * v.z; acc.w += a * v.w;
    }
    __shared__ float sm2[8][128];
    *reinterpret_cast<float4*>(&sm2[kg][d4]) = acc;
    __syncthreads();
    if (t < 128) {
        float s0 = 0.f;
#pragma unroll
        for (int g = 0; g < 8; ++g) s0 += sm2[g][t];
        pctx[((size_t)bh * 32 + s) * 128 + t] = s0;
    }
}

// ---------- K6: reduce context partials ----------
__global__ __launch_bounds__(128) void ctx_reduce_kernel(
        const float* __restrict__ pctx, float* __restrict__ out) {
    const int bh = blockIdx.x;
    const int t = threadIdx.x;
    float acc = 0.f;
    for (int s2 = 0; s2 < 32; ++s2) acc += pctx[((size_t)bh * 32 + s2) * 128 + t];
    out[(size_t)bh * 128 + t] = acc;
}

extern "C" void kernel_launch(void* const* d_in, const int* in_sizes, int n_in,
                              void* d_out, int out_size, void* d_ws, size_t ws_size,
                              hipStream_t stream) {
    const float* query   = (const float*)d_in[0];
    const float* key_in  = (const float*)d_in[1];
    const float* value   = (const float*)d_in[2];
    const float* pa      = (const float*)d_in[3];
    const float* conv_w  = (const float*)d_in[4];
    const float* conv_b  = (const float*)d_in[5];
    const float* w_u     = (const float*)d_in[6];
    const float* w_q     = (const float*)d_in[7];
    const float* w_v     = (const float*)d_in[8];
    const float* bias    = (const float*)d_in[9];
    const float* score_w = (const float*)d_in[10];
    const float* score_b = (const float*)d_in[11];

    float* out = (float*)d_out;
    float* ctx_out = out;                 // [128,128]
    float* align_out = out + 16384;       // [16,8,4096]

    char* ws = (char*)d_ws;
    const size_t OFF_Q    = 0;                        // 64 KB
    const size_t OFF_LOC  = 65536;                    // 2.62 MB
    const size_t OFF_WVT  = OFF_LOC + 2621440;        // 2 MB (tiled bf16)
    const size_t OFF_PCTX = OFF_WVT + 2097152;        // 2 MB
    const size_t OFF_LE   = OFF_PCTX + 2097152;       // 33.55 MB
    const size_t OFF_KBF  = OFF_LE + 33554432;        // 128 MB (tiled bf16)
    const size_t NEED_FULL = OFF_KBF + 134217728;
    const size_t NEED_LE   = OFF_KBF;

    float* ws_q            = (float*)(ws + OFF_Q);
    float* ws_loc          = (float*)(ws + OFF_LOC);
    unsigned short* ws_wvT = (unsigned short*)(ws + OFF_WVT);
    float* ws_pctx         = (float*)(ws + OFF_PCTX);
    float* ws_le           = (float*)(ws + OFF_LE);
    unsigned short* ws_kbf = (unsigned short*)(ws + OFF_KBF);

    hipLaunchKernelGGL(wv_tile_kernel, dim3(8, 32), dim3(256), 0, stream, w_v, ws_wvT);
    hipLaunchKernelGGL(qproj_kernel, dim3(128), dim3(128), 0, stream, query, w_q, ws_q);
    hipLaunchKernelGGL(loc_conv_kernel, dim3(16, 16), dim3(256), 0, stream, pa, conv_w, conv_b, ws_loc);

    if (ws_size >= NEED_FULL) {
        hipLaunchKernelGGL(loc_energy_kernel, dim3(16, 32), dim3(256), 0, stream, ws_loc, w_u, ws_le);
        hipLaunchKernelGGL(key_tile_kernel, dim3(512, 32), dim3(256), 0, stream, key_in, ws_kbf);
        hipLaunchKernelGGL((gemm_score_kernel<0>), dim3(4096), dim3(256), 0, stream,
                           key_in, ws_kbf, ws_wvT, ws_le, ws_q, ws_loc, w_u, bias, score_w, score_b, align_out);
    } else if (ws_size >= NEED_LE) {
        hipLaunchKernelGGL(loc_energy_kernel, dim3(16, 32), dim3(256), 0, stream, ws_loc, w_u, ws_le);
        hipLaunchKernelGGL((gemm_score_kernel<1>), dim3(4096), dim3(256), 0, stream,
                           key_in, ws_kbf, ws_wvT, ws_le, ws_q, ws_loc, w_u, bias, score_w, score_b, align_out);
    } else {
        hipLaunchKernelGGL((gemm_score_kernel<2>), dim3(4096), dim3(256), 0, stream,
                           key_in, ws_kbf, ws_wvT, ws_le, ws_q, ws_loc, w_u, bias, score_w, score_b, align_out);
    }
    hipLaunchKernelGGL(softmax_kernel, dim3(128), dim3(256), 0, stream, align_out);
    hipLaunchKernelGGL(ctx_partial_kernel, dim3(32, 128), dim3(256), 0, stream, value, align_out, ws_pctx);
    hipLaunchKernelGGL(ctx_reduce_kernel, dim3(128), dim3(128), 0, stream, ws_pctx, ctx_out);
}

// Round 4
// 432.395 us; speedup vs baseline: 1.0679x; 1.0679x over previous
//
#include <hip/hip_runtime.h>
#include <hip/hip_bf16.h>
#include <cstdint>

typedef __attribute__((ext_vector_type(8))) short bf16x8;
typedef __attribute__((ext_vector_type(4))) float f32x4;
typedef __attribute__((ext_vector_type(4))) unsigned short u16x4;
typedef __attribute__((ext_vector_type(8))) unsigned short u16x8;

__device__ __forceinline__ unsigned short f2bf(float f) {
    unsigned int u = __float_as_uint(f);
    unsigned int r = (u + 0x7fffu + ((u >> 16) & 1u)) >> 16;
    return (unsigned short)r;
}

__device__ __forceinline__ float tanh_fast(float x) {
    return 1.0f - 2.0f / (__expf(2.0f * x) + 1.0f);
}

#define GLDS(SRC, DST) __builtin_amdgcn_global_load_lds(                         \
        (const __attribute__((address_space(1))) void*)(SRC),                    \
        (__attribute__((address_space(3))) void*)(DST), 16, 0, 0)

// ---------- K-1: fp32 -> bf16 convert of key_in into FRAGMENT-TILED layout ----
__global__ __launch_bounds__(256) void key_tile_kernel(
        const float* __restrict__ in, unsigned short* __restrict__ out) {
    const int panel = blockIdx.x;   // 0..511
    const int kt = blockIdx.y;      // 0..31
    const int t = threadIdx.x;
#pragma unroll
    for (int cc = 0; cc < 2; ++cc) {
        const int c = cc * 256 + t;
        const int rb = c >> 6, kg = (c >> 4) & 3, r = c & 15;
        const size_t R = (size_t)panel * 128 + rb * 16 + r;
        const float* src = in + R * 1024 + kt * 32 + kg * 8;
        const float4 v0 = *reinterpret_cast<const float4*>(src);
        const float4 v1 = *reinterpret_cast<const float4*>(src + 4);
        u16x8 u;
        u[0] = f2bf(v0.x); u[1] = f2bf(v0.y); u[2] = f2bf(v0.z); u[3] = f2bf(v0.w);
        u[4] = f2bf(v1.x); u[5] = f2bf(v1.y); u[6] = f2bf(v1.z); u[7] = f2bf(v1.w);
        *reinterpret_cast<u16x8*>(out + (((size_t)panel * 32 + kt) * 512 + c) * 8) = u;
    }
}

// ---------- K0: w_v -> bf16 fragment-tiled B ----------
__global__ __launch_bounds__(256) void wv_tile_kernel(
        const float* __restrict__ wv, unsigned short* __restrict__ out) {
    __shared__ float tile[32][129];
    const int h = blockIdx.x;    // 0..7
    const int kt = blockIdx.y;   // 0..31
    const int t = threadIdx.x;
    for (int i = t; i < 1024; i += 256) {
        const int fl = i >> 5;
        const int e4 = (i & 31) * 4;
        const float4 v = *reinterpret_cast<const float4*>(
            wv + (size_t)(kt * 32 + fl) * 1024 + h * 128 + e4);
        tile[fl][e4 + 0] = v.x; tile[fl][e4 + 1] = v.y;
        tile[fl][e4 + 2] = v.z; tile[fl][e4 + 3] = v.w;
    }
    __syncthreads();
#pragma unroll
    for (int cc2 = 0; cc2 < 2; ++cc2) {
        const int c = cc2 * 256 + t;
        const int cb = c >> 6, kg = (c >> 4) & 3, ccl = c & 15;
        const int e_local = cb * 16 + ccl;
        u16x8 u;
#pragma unroll
        for (int j = 0; j < 8; ++j) u[j] = f2bf(tile[kg * 8 + j][e_local]);
        *reinterpret_cast<u16x8*>(out + (((size_t)h * 32 + kt) * 512 + c) * 8) = u;
    }
}

// ---------- K1: q projection ----------
__global__ __launch_bounds__(128) void qproj_kernel(
        const float* __restrict__ query, const float* __restrict__ w_q,
        float* __restrict__ ws_q) {
    __shared__ float qs[1024];
    int bh = blockIdx.x;
    int b = bh >> 3, h = bh & 7;
    int t = threadIdx.x;
    for (int i = t; i < 1024; i += 128) qs[i] = query[(size_t)b * 1024 + i];
    __syncthreads();
    float acc = 0.f;
    const float* wcol = w_q + h * 128 + t;
    for (int f = 0; f < 1024; ++f) acc += qs[f] * wcol[(size_t)f * 1024];
    ws_q[(size_t)bh * 128 + t] = acc;
}

// ---------- K2: conv1d location features ----------
__global__ __launch_bounds__(256) void loc_conv_kernel(
        const float* __restrict__ pa, const float* __restrict__ conv_w,
        const float* __restrict__ conv_b, float* __restrict__ ws_loc) {
    __shared__ float pas[8][258];
    __shared__ float cw[240];
    __shared__ float cb[16];
    int b = blockIdx.x, k0 = blockIdx.y * 256;
    int t = threadIdx.x;
    for (int i = t; i < 8 * 258; i += 256) {
        int hh = i / 258, kk = i % 258;
        int gk = k0 + kk - 1;
        pas[hh][kk] = (gk >= 0 && gk < 4096) ? pa[((size_t)(b * 8 + hh)) * 4096 + gk] : 0.f;
    }
    if (t < 240) cw[t] = conv_w[t];
    if (t < 10) cb[t] = conv_b[t];
    __syncthreads();
#pragma unroll
    for (int c = 0; c < 10; ++c) {
        float acc = cb[c];
#pragma unroll
        for (int hh = 0; hh < 8; ++hh) {
            acc += pas[hh][t] * cw[(c * 8 + hh) * 3 + 0]
                 + pas[hh][t + 1] * cw[(c * 8 + hh) * 3 + 1]
                 + pas[hh][t + 2] * cw[(c * 8 + hh) * 3 + 2];
        }
        ws_loc[((size_t)(b * 10 + c)) * 4096 + k0 + t] = acc;
    }
}

// ---------- K2b: le[b,k,d] = tanh(sum_c loc[b,c,k]*w_u[c,d]) ----------
__global__ __launch_bounds__(256) void loc_energy_kernel(
        const float* __restrict__ ws_loc, const float* __restrict__ w_u,
        float* __restrict__ le) {
    __shared__ float loc_s[10][128];
    __shared__ float wu_s[10][128];
    const int b = blockIdx.x, k0 = blockIdx.y * 128;
    const int t = threadIdx.x;
    for (int i = t; i < 1280; i += 256) {
        const int c = i >> 7, r = i & 127;
        loc_s[c][r] = ws_loc[((size_t)(b * 10 + c)) * 4096 + k0 + r];
        wu_s[c][r] = w_u[i];
    }
    __syncthreads();
    const int k = t >> 1;
    const int d0 = (t & 1) * 64;
    float lc[10];
#pragma unroll
    for (int c = 0; c < 10; ++c) lc[c] = loc_s[c][k];
    float* dst = le + ((size_t)(b * 4096) + k0 + k) * 128 + d0;
#pragma unroll
    for (int dd = 0; dd < 64; dd += 4) {
        float4 o;
#pragma unroll
        for (int j = 0; j < 4; ++j) {
            float s = 0.f;
#pragma unroll
            for (int c = 0; c < 10; ++c) s += lc[c] * wu_s[c][d0 + dd + j];
            ((float*)&o)[j] = tanh_fast(s);
        }
        *reinterpret_cast<float4*>(dst + dd) = o;
    }
}

// ---------- K3: fused bf16 MFMA GEMM + energy + score ----------
// BM=128, BN=128 (one head), BK=32; 4 waves 2x2; dbuf; fragment-tiled LDS.
template<int AMODE>
__global__ __launch_bounds__(256) void gemm_score_kernel(
        const float* __restrict__ key_f32, const unsigned short* __restrict__ key_tiled,
        const unsigned short* __restrict__ wvT_tiled,
        const float* __restrict__ le,
        const float* __restrict__ ws_q, const float* __restrict__ ws_loc,
        const float* __restrict__ w_u, const float* __restrict__ bias,
        const float* __restrict__ score_w, const float* __restrict__ score_b,
        float* __restrict__ align_out) {
    __shared__ __align__(16) unsigned short As[2][4096];
    __shared__ __align__(16) unsigned short Bs[2][4096];
    __shared__ float loc_sm[AMODE == 2 ? 1280 : 1];
    __shared__ float wu_sm[AMODE == 2 ? 1280 : 1];
    __shared__ float qb_sm[128], sw_sm[128];
    __shared__ float partial[256];

    const int t = threadIdx.x;
    const int lane = t & 63, wid = t >> 6;
    const int wm = wid >> 1, wn = wid & 1;

    // XCD swizzle: 8 head-blocks of one A-panel contiguous on one XCD
    const int fid = blockIdx.x;
    const int x = fid & 7, j = fid >> 3;
    const int bm = x * 64 + (j >> 3);
    const int h = j & 7;
    const int b = bm >> 5;
    const int kk0 = (bm & 31) << 7;

    if (t < 128) {
        qb_sm[t] = ws_q[(size_t)(b * 8 + h) * 128 + t] + bias[t];
        sw_sm[t] = score_w[t];
    }
    if (AMODE == 2) {
        for (int i = t; i < 1280; i += 256) {
            int c = i >> 7, r = i & 127;
            loc_sm[i] = ws_loc[((size_t)(b * 10 + c)) * 4096 + kk0 + r];
            wu_sm[i] = w_u[i];
        }
    }

    const unsigned short* aT = key_tiled + ((size_t)(b * 32 + (kk0 >> 7))) * 131072;
    const unsigned short* bT = wvT_tiled + (size_t)h * 131072;
    const float* aBaseF = key_f32 + ((size_t)(b * 4096 + kk0)) * 1024;

    f32x4 acc[4][4] = {};
    int cur = 0;

#define STAGE_B(BUF, KT) {                                                        \
        GLDS(bT + (KT) * 4096 + t * 8, &Bs[BUF][t * 8]);                          \
        GLDS(bT + (KT) * 4096 + 2048 + t * 8, &Bs[BUF][2048 + t * 8]); }

#define STAGE_A(BUF, KT) {                                                        \
        if (AMODE == 0) {                                                         \
            GLDS(aT + (KT) * 4096 + t * 8, &As[BUF][t * 8]);                      \
            GLDS(aT + (KT) * 4096 + 2048 + t * 8, &As[BUF][2048 + t * 8]);        \
        } else {                                                                  \
            _Pragma("unroll")                                                     \
            for (int cc_ = 0; cc_ < 2; ++cc_) {                                   \
                const int c_ = cc_ * 256 + t;                                     \
                const int rb_ = c_ >> 6, kg_ = (c_ >> 4) & 3, r_ = c_ & 15;       \
                const float* s_ = aBaseF + (size_t)(rb_ * 16 + r_) * 1024         \
                                  + (KT) * 32 + kg_ * 8;                          \
                const float4 v0_ = *reinterpret_cast<const float4*>(s_);          \
                const float4 v1_ = *reinterpret_cast<const float4*>(s_ + 4);      \
                u16x8 u_;                                                         \
                u_[0] = f2bf(v0_.x); u_[1] = f2bf(v0_.y);                         \
                u_[2] = f2bf(v0_.z); u_[3] = f2bf(v0_.w);                         \
                u_[4] = f2bf(v1_.x); u_[5] = f2bf(v1_.y);                         \
                u_[6] = f2bf(v1_.z); u_[7] = f2bf(v1_.w);                         \
                *reinterpret_cast<u16x8*>(&As[BUF][c_ * 8]) = u_;                 \
            }                                                                     \
        } }

    STAGE_A(0, 0);
    STAGE_B(0, 0);
    __syncthreads();

    for (int kt = 0; kt < 32; ++kt) {
        if (kt < 31) {
            STAGE_A(cur ^ 1, kt + 1);
            STAGE_B(cur ^ 1, kt + 1);
        }
        bf16x8 af[4], bg[4];
#pragma unroll
        for (int mf = 0; mf < 4; ++mf)
            af[mf] = *reinterpret_cast<const bf16x8*>(&As[cur][(wm * 4 + mf) * 512 + lane * 8]);
#pragma unroll
        for (int nf = 0; nf < 4; ++nf)
            bg[nf] = *reinterpret_cast<const bf16x8*>(&Bs[cur][(wn * 4 + nf) * 512 + lane * 8]);
#pragma unroll
        for (int mf = 0; mf < 4; ++mf)
#pragma unroll
            for (int nf = 0; nf < 4; ++nf)
                acc[mf][nf] = __builtin_amdgcn_mfma_f32_16x16x32_bf16(
                    af[mf], bg[nf], acc[mf][nf], 0, 0, 0);
        __syncthreads();
        cur ^= 1;
    }

    // ---- epilogue: score = sum_d tanh(kproj + q + bias + le) * sw ----
    // tanh(x) = 1 - 2/(exp2(K2*x)+1), K2 = 2*log2(e). K2 folded into FMAs.
    const float K2 = 2.8853900817779268f;
    const float sb = score_b[0];
    float kqb[4], swv[4];
#pragma unroll
    for (int nf = 0; nf < 4; ++nf) {
        const int d = wn * 64 + nf * 16 + (lane & 15);
        kqb[nf] = qb_sm[d] * K2;
        swv[nf] = sw_sm[d];
    }
    // le base for this thread: row = b*4096+kk0 + wm*64 + (lane>>4)*4 (+mf*16+jj), d = wn*64+(lane&15) (+nf*16)
    const float* leB = le + ((size_t)(b * 4096 + kk0) + wm * 64 + ((lane >> 4) << 2)) * 128
                       + wn * 64 + (lane & 15);

#pragma unroll
    for (int mf = 0; mf < 4; ++mf) {
        float lv[16];
        if (AMODE != 2) {
#pragma unroll
            for (int jj = 0; jj < 4; ++jj)
#pragma unroll
                for (int nf = 0; nf < 4; ++nf)
                    lv[jj * 4 + nf] = leB[(size_t)(mf * 16 + jj) * 128 + nf * 16];
        }
#pragma unroll
        for (int jj = 0; jj < 4; ++jj) {
            const int row_l = wm * 64 + mf * 16 + ((lane >> 4) << 2) + jj;
            float sum = 0.f;
#pragma unroll
            for (int nf = 0; nf < 4; ++nf) {
                float lev;
                if (AMODE == 2) {
                    const int d = wn * 64 + nf * 16 + (lane & 15);
                    float lr = 0.f;
#pragma unroll
                    for (int c = 0; c < 10; ++c)
                        lr += loc_sm[c * 128 + row_l] * wu_sm[c * 128 + d];
                    lev = tanh_fast(lr);
                } else {
                    lev = lv[jj * 4 + nf];
                }
                const float m = fmaf(K2, lev, kqb[nf]);
                const float tt = fmaf(K2, acc[mf][nf][jj], m);
                const float y = __builtin_amdgcn_exp2f(tt);
                const float r = fmaf(-2.0f, __builtin_amdgcn_rcpf(y + 1.0f), 1.0f);
                sum = fmaf(r, swv[nf], sum);
            }
            sum += __shfl_xor(sum, 1);
            sum += __shfl_xor(sum, 2);
            sum += __shfl_xor(sum, 4);
            sum += __shfl_xor(sum, 8);
            if ((lane & 15) == 0) partial[row_l * 2 + wn] = sum;
        }
    }
    __syncthreads();
    if (t < 128) {
        align_out[(size_t)(b * 8 + h) * 4096 + kk0 + t] = partial[t * 2] + partial[t * 2 + 1] + sb;
    }
}

// ---------- K4: softmax over k ----------
__global__ __launch_bounds__(256) void softmax_kernel(float* __restrict__ align_o) {
    const int bh = blockIdx.x;
    float* row = align_o + (size_t)bh * 4096;
    const int t = threadIdx.x;
    float v[16];
    float m = -1e30f;
#pragma unroll
    for (int i = 0; i < 16; ++i) {
        v[i] = row[i * 256 + t];
        m = fmaxf(m, v[i]);
    }
#pragma unroll
    for (int off = 32; off; off >>= 1) m = fmaxf(m, __shfl_xor(m, off));
    __shared__ float sm[4], ss[4];
    const int wid = t >> 6;
    if ((t & 63) == 0) sm[wid] = m;
    __syncthreads();
    m = fmaxf(fmaxf(sm[0], sm[1]), fmaxf(sm[2], sm[3]));
    float s = 0.f;
#pragma unroll
    for (int i = 0; i < 16; ++i) {
        v[i] = __expf(v[i] - m);
        s += v[i];
    }
#pragma unroll
    for (int off = 32; off; off >>= 1) s += __shfl_xor(s, off);
    if ((t & 63) == 0) ss[wid] = s;
    __syncthreads();
    s = ss[0] + ss[1] + ss[2] + ss[3];
    const float inv = 1.f / s;
#pragma unroll
    for (int i = 0; i < 16; ++i) row[i * 256 + t] = v[i] * inv;
}

// ---------- K5: split-K context partials (float4) ----------
__global__ __launch_bounds__(256) void ctx_partial_kernel(
        const float* __restrict__ value, const float* __restrict__ align_o,
        float* __restrict__ pctx) {
    const int s = blockIdx.x;    // 0..31
    const int bh = blockIdx.y;   // 0..127
    const int b = bh >> 3, h = bh & 7;
    const int t = threadIdx.x;
    const int d4 = (t & 31) * 4;
    const int kg = t >> 5;       // 0..7
    const float* arow = align_o + (size_t)bh * 4096 + s * 128;
    const float* vbase = value + ((size_t)(b * 4096 + s * 128)) * 1024 + h * 128 + d4;
    float4 acc = {0.f, 0.f, 0.f, 0.f};
    for (int i = 0; i < 16; ++i) {
        const int kk = i * 8 + kg;
        const float a = arow[kk];
        const float4 v = *reinterpret_cast<const float4*>(vbase + (size_t)kk * 1024);
        acc.x += a * v.x; acc.y += a * v.y; acc.z += a * v.z; acc.w += a * v.w;
    }
    __shared__ float sm2[8][128];
    *reinterpret_cast<float4*>(&sm2[kg][d4]) = acc;
    __syncthreads();
    if (t < 128) {
        float s0 = 0.f;
#pragma unroll
        for (int g = 0; g < 8; ++g) s0 += sm2[g][t];
        pctx[((size_t)bh * 32 + s) * 128 + t] = s0;
    }
}

// ---------- K6: reduce context partials ----------
__global__ __launch_bounds__(128) void ctx_reduce_kernel(
        const float* __restrict__ pctx, float* __restrict__ out) {
    const int bh = blockIdx.x;
    const int t = threadIdx.x;
    float acc = 0.f;
    for (int s2 = 0; s2 < 32; ++s2) acc += pctx[((size_t)bh * 32 + s2) * 128 + t];
    out[(size_t)bh * 128 + t] = acc;
}

extern "C" void kernel_launch(void* const* d_in, const int* in_sizes, int n_in,
                              void* d_out, int out_size, void* d_ws, size_t ws_size,
                              hipStream_t stream) {
    const float* query   = (const float*)d_in[0];
    const float* key_in  = (const float*)d_in[1];
    const float* value   = (const float*)d_in[2];
    const float* pa      = (const float*)d_in[3];
    const float* conv_w  = (const float*)d_in[4];
    const float* conv_b  = (const float*)d_in[5];
    const float* w_u     = (const float*)d_in[6];
    const float* w_q     = (const float*)d_in[7];
    const float* w_v     = (const float*)d_in[8];
    const float* bias    = (const float*)d_in[9];
    const float* score_w = (const float*)d_in[10];
    const float* score_b = (const float*)d_in[11];

    float* out = (float*)d_out;
    float* ctx_out = out;                 // [128,128]
    float* align_out = out + 16384;       // [16,8,4096]

    char* ws = (char*)d_ws;
    const size_t OFF_Q    = 0;                        // 64 KB
    const size_t OFF_LOC  = 65536;                    // 2.62 MB
    const size_t OFF_WVT  = OFF_LOC + 2621440;        // 2 MB (tiled bf16)
    const size_t OFF_PCTX = OFF_WVT + 2097152;        // 2 MB
    const size_t OFF_LE   = OFF_PCTX + 2097152;       // 33.55 MB
    const size_t OFF_KBF  = OFF_LE + 33554432;        // 128 MB (tiled bf16)
    const size_t NEED_FULL = OFF_KBF + 134217728;
    const size_t NEED_LE   = OFF_KBF;

    float* ws_q            = (float*)(ws + OFF_Q);
    float* ws_loc          = (float*)(ws + OFF_LOC);
    unsigned short* ws_wvT = (unsigned short*)(ws + OFF_WVT);
    float* ws_pctx         = (float*)(ws + OFF_PCTX);
    float* ws_le           = (float*)(ws + OFF_LE);
    unsigned short* ws_kbf = (unsigned short*)(ws + OFF_KBF);

    hipLaunchKernelGGL(wv_tile_kernel, dim3(8, 32), dim3(256), 0, stream, w_v, ws_wvT);
    hipLaunchKernelGGL(qproj_kernel, dim3(128), dim3(128), 0, stream, query, w_q, ws_q);
    hipLaunchKernelGGL(loc_conv_kernel, dim3(16, 16), dim3(256), 0, stream, pa, conv_w, conv_b, ws_loc);

    if (ws_size >= NEED_FULL) {
        hipLaunchKernelGGL(loc_energy_kernel, dim3(16, 32), dim3(256), 0, stream, ws_loc, w_u, ws_le);
        hipLaunchKernelGGL(key_tile_kernel, dim3(512, 32), dim3(256), 0, stream, key_in, ws_kbf);
        hipLaunchKernelGGL((gemm_score_kernel<0>), dim3(4096), dim3(256), 0, stream,
                           key_in, ws_kbf, ws_wvT, ws_le, ws_q, ws_loc, w_u, bias, score_w, score_b, align_out);
    } else if (ws_size >= NEED_LE) {
        hipLaunchKernelGGL(loc_energy_kernel, dim3(16, 32), dim3(256), 0, stream, ws_loc, w_u, ws_le);
        hipLaunchKernelGGL((gemm_score_kernel<1>), dim3(4096), dim3(256), 0, stream,
                           key_in, ws_kbf, ws_wvT, ws_le, ws_q, ws_loc, w_u, bias, score_w, score_b, align_out);
    } else {
        hipLaunchKernelGGL((gemm_score_kernel<2>), dim3(4096), dim3(256), 0, stream,
                           key_in, ws_kbf, ws_wvT, ws_le, ws_q, ws_loc, w_u, bias, score_w, score_b, align_out);
    }
    hipLaunchKernelGGL(softmax_kernel, dim3(128), dim3(256), 0, stream, align_out);
    hipLaunchKernelGGL(ctx_partial_kernel, dim3(32, 128), dim3(256), 0, stream, value, align_out, ws_pctx);
    hipLaunchKernelGGL(ctx_reduce_kernel, dim3(128), dim3(128), 0, stream, ws_pctx, ctx_out);
}